// Round 6
// baseline (433.120 us; speedup 1.0000x reference)
//
#include <hip/hip_runtime.h>
#include <math.h>

#define F_IN 128
#define HDIM 256
#define CDIM 32
#define SCHUNK 1024
#define RSH 3          // dsts per coarse bucket = 8
#define GRP 512        // dsts per group = 64 buckets

typedef __attribute__((ext_vector_type(8))) short s16x8;
typedef __attribute__((ext_vector_type(4))) float f32x4;

__device__ __forceinline__ unsigned bf16_rne(float f) {
  unsigned u = __float_as_uint(f);
  u += 0x7fffu + ((u >> 16) & 1u);
  return u >> 16;
}
__device__ __forceinline__ unsigned pack2(float lo, float hi) {
  return (bf16_rne(hi) << 16) | bf16_rne(lo);
}
__device__ __forceinline__ float bflo(unsigned u) { return __uint_as_float(u << 16); }
__device__ __forceinline__ float bfhi(unsigned u) { return __uint_as_float(u & 0xffff0000u); }

// ---------------- bucket build ----------------
__global__ void k_bcount(const int* __restrict__ ei, int* __restrict__ bcnt, int E) {
  int e = blockIdx.x * blockDim.x + threadIdx.x;
  if (e < E) atomicAdd(&bcnt[ei[(size_t)E + e] >> RSH], 1);
}

// coalesced multi-round scan of bucket counts (int4 per thread per round)
__global__ __launch_bounds__(1024) void k_bscan(const int4* __restrict__ bcnt4,
                                                int* __restrict__ boffs,
                                                int* __restrict__ bcur,
                                                int n4, int nbuc, int Etot) {
  __shared__ int sh[1024];
  __shared__ int basev;
  int tid = threadIdx.x;
  if (tid == 0) basev = 0;
  __syncthreads();
  for (int r0 = 0; r0 < n4; r0 += 1024) {
    int j = r0 + tid;
    int4 v = (j < n4) ? bcnt4[j] : make_int4(0, 0, 0, 0);
    int s = v.x + v.y + v.z + v.w;
    sh[tid] = s;
    __syncthreads();
    for (int off = 1; off < 1024; off <<= 1) {
      int t = (tid >= off) ? sh[tid - off] : 0;
      __syncthreads();
      sh[tid] += t;
      __syncthreads();
    }
    if (j < n4) {
      int run = basev + sh[tid] - s;
      int4 o;
      o.x = run; run += v.x;
      o.y = run; run += v.y;
      o.z = run; run += v.z;
      o.w = run;
      ((int4*)boffs)[j] = o;
      ((int4*)bcur)[j] = o;
    }
    __syncthreads();
    if (tid == 1023) basev += sh[1023];
    __syncthreads();
  }
  if (tid == 0) boffs[nbuc] = Etot;
}

__global__ void k_bscatter(const int* __restrict__ ei, int* __restrict__ bcur,
                           unsigned* __restrict__ barray, int E) {
  int e = blockIdx.x * blockDim.x + threadIdx.x;
  if (e >= E) return;
  int s = ei[e];
  int d = ei[(size_t)E + e];
  int pos = atomicAdd(&bcur[d >> RSH], 1);
  barray[pos] = ((unsigned)s << 9) | (unsigned)(d & (GRP - 1));
}

// per-group LDS histogram -> cnt + dinv (coalesced writes, no global atomics)
__global__ __launch_bounds__(256) void k_cntfine(const unsigned* __restrict__ barray,
                                                 const int* __restrict__ boffs,
                                                 int* __restrict__ cnt,
                                                 float* __restrict__ dinv,
                                                 int N, int nbuc) {
  __shared__ int hist[GRP];
  int g = blockIdx.x;
  int tid = threadIdx.x;
  for (int i = tid; i < GRP; i += 256) hist[i] = 0;
  __syncthreads();
  int b0 = g * (GRP >> RSH);
  int b1 = b0 + (GRP >> RSH);
  if (b1 > nbuc) b1 = nbuc;
  if (b0 > nbuc) b0 = nbuc;
  int e0 = boffs[b0], e1 = boffs[b1];
  for (int i = e0 + tid; i < e1; i += 256)
    atomicAdd(&hist[barray[i] & (GRP - 1)], 1);
  __syncthreads();
  int d0 = g * GRP;
  for (int i = tid; i < GRP; i += 256) {
    int d = d0 + i;
    if (d < N) {
      int c = hist[i];
      cnt[d] = c;
      dinv[d] = rsqrtf((float)c + 1.0f);
    }
  }
}

// ---------------- scan of per-dst counts -> offs ----------------
__global__ __launch_bounds__(256) void k_part(const int* __restrict__ cnt,
                                              int* __restrict__ part, int N) {
  __shared__ int red[256];
  int tid = threadIdx.x;
  int base = blockIdx.x * SCHUNK + tid * 4;
  int s = 0;
#pragma unroll
  for (int i = 0; i < 4; ++i) {
    int idx = base + i;
    if (idx < N) s += cnt[idx];
  }
  red[tid] = s;
  __syncthreads();
  for (int off = 128; off >= 1; off >>= 1) {
    if (tid < off) red[tid] += red[tid + off];
    __syncthreads();
  }
  if (tid == 0) part[blockIdx.x] = red[0];
}

__global__ __launch_bounds__(1024) void k_scanpart(int* __restrict__ part,
                                                   int* __restrict__ offs,
                                                   int nb, int N, int Etot) {
  __shared__ int sh[1024];
  int tid = threadIdx.x;
  int v = (tid < nb) ? part[tid] : 0;
  sh[tid] = v;
  __syncthreads();
  for (int off = 1; off < 1024; off <<= 1) {
    int t = (tid >= off) ? sh[tid - off] : 0;
    __syncthreads();
    sh[tid] += t;
    __syncthreads();
  }
  if (tid < nb) part[tid] = sh[tid] - v;
  if (tid == 0) offs[N] = Etot;
}

__global__ __launch_bounds__(256) void k_offs(const int* __restrict__ cnt,
                                              const int* __restrict__ part,
                                              int* __restrict__ offs, int N) {
  __shared__ int sh[256];
  int tid = threadIdx.x;
  int base = blockIdx.x * SCHUNK + tid * 4;
  int v[4];
  int s = 0;
#pragma unroll
  for (int i = 0; i < 4; ++i) {
    int idx = base + i;
    v[i] = (idx < N) ? cnt[idx] : 0;
    s += v[i];
  }
  sh[tid] = s;
  __syncthreads();
  for (int off = 1; off < 256; off <<= 1) {
    int t = (tid >= off) ? sh[tid - off] : 0;
    __syncthreads();
    sh[tid] += t;
    __syncthreads();
  }
  int run = part[blockIdx.x] + sh[tid] - s;
#pragma unroll
  for (int i = 0; i < 4; ++i) {
    int idx = base + i;
    if (idx < N) {
      offs[idx] = run;
      run += v[i];
    }
  }
}

// per-group fine fill: LDS cursors, writes confined to one contiguous region/CU
__global__ __launch_bounds__(256) void k_fillfine(const unsigned* __restrict__ barray,
                                                  const int* __restrict__ boffs,
                                                  const int* __restrict__ offs,
                                                  const float* __restrict__ dinv,
                                                  int2* __restrict__ srcs2,
                                                  int N, int nbuc) {
  __shared__ int cur[GRP];
  int g = blockIdx.x;
  int tid = threadIdx.x;
  int d0 = g * GRP;
  for (int i = tid; i < GRP; i += 256) {
    int d = d0 + i;
    cur[i] = (d < N) ? offs[d] : 0;
  }
  __syncthreads();
  int b0 = g * (GRP >> RSH);
  int b1 = b0 + (GRP >> RSH);
  if (b1 > nbuc) b1 = nbuc;
  if (b0 > nbuc) b0 = nbuc;
  int e0 = boffs[b0], e1 = boffs[b1];
  for (int i = e0 + tid; i < e1; i += 256) {
    unsigned p = barray[i];
    int dl = p & (GRP - 1);
    int src = p >> 9;
    int pos = atomicAdd(&cur[dl], 1);
    int2 v;
    v.x = src;
    v.y = __float_as_int(dinv[src]);
    srcs2[pos] = v;
  }
}

// ---------------- conversions ----------------
__global__ void k_cvt_x(const float2* __restrict__ x, unsigned* __restrict__ xh, long long n2) {
  long long i = (long long)blockIdx.x * blockDim.x + threadIdx.x;
  if (i >= n2) return;
  float2 v = x[i];
  xh[i] = pack2(v.x, v.y);
}

__global__ void k_cvt_w(const float* __restrict__ W1, const float* __restrict__ W2,
                        short* __restrict__ W1t, short* __restrict__ W2t) {
  int t = blockIdx.x * blockDim.x + threadIdx.x;
  if (t < F_IN * HDIM) {
    int c = t >> 7, k = t & 127;
    W1t[t] = (short)bf16_rne(W1[k * HDIM + c]);
  } else {
    int t2 = t - F_IN * HDIM;
    if (t2 < HDIM * CDIM) {
      int n = t2 >> 8, k = t2 & 255;
      W2t[t2] = (short)bf16_rne(W2[k * CDIM + n]);
    }
  }
}

// ---------------- layer-1 aggregation: full wave/row, even/odd edge halves ----------------
__global__ __launch_bounds__(256) void k_agg1(const uint2* __restrict__ xh2,
                                              const int2* __restrict__ srcs2,
                                              const int* __restrict__ offs,
                                              const float* __restrict__ dinv,
                                              uint2* __restrict__ aggh2, int N) {
  int row = (blockIdx.x * 256 + threadIdx.x) >> 6;
  int lane = threadIdx.x & 63;
  if (row >= N) return;
  int half = lane >> 5;
  int sl = lane & 31;
  float dd = dinv[row];
  float a0 = 0.f, a1 = 0.f, a2 = 0.f, a3 = 0.f;
  if (half == 0) {
    uint2 u = xh2[(size_t)row * 32 + sl];
    float sc = dd * dd;
    a0 = bflo(u.x) * sc; a1 = bfhi(u.x) * sc;
    a2 = bflo(u.y) * sc; a3 = bfhi(u.y) * sc;
  }
  int beg = offs[row], end = offs[row + 1];
  int k = beg + half;
  for (; k + 2 < end; k += 4) {
    int2 s0 = srcs2[k];
    int2 s1 = srcs2[k + 2];
    uint2 v0 = xh2[(size_t)s0.x * 32 + sl];
    uint2 v1 = xh2[(size_t)s1.x * 32 + sl];
    float n0 = __int_as_float(s0.y) * dd;
    float n1 = __int_as_float(s1.y) * dd;
    a0 = fmaf(bflo(v0.x), n0, a0); a1 = fmaf(bfhi(v0.x), n0, a1);
    a2 = fmaf(bflo(v0.y), n0, a2); a3 = fmaf(bfhi(v0.y), n0, a3);
    a0 = fmaf(bflo(v1.x), n1, a0); a1 = fmaf(bfhi(v1.x), n1, a1);
    a2 = fmaf(bflo(v1.y), n1, a2); a3 = fmaf(bfhi(v1.y), n1, a3);
  }
  if (k < end) {
    int2 s0 = srcs2[k];
    uint2 v0 = xh2[(size_t)s0.x * 32 + sl];
    float n0 = __int_as_float(s0.y) * dd;
    a0 = fmaf(bflo(v0.x), n0, a0); a1 = fmaf(bfhi(v0.x), n0, a1);
    a2 = fmaf(bflo(v0.y), n0, a2); a3 = fmaf(bfhi(v0.y), n0, a3);
  }
  a0 += __shfl_xor(a0, 32, 64);
  a1 += __shfl_xor(a1, 32, 64);
  a2 += __shfl_xor(a2, 32, 64);
  a3 += __shfl_xor(a3, 32, 64);
  if (half == 0) {
    uint2 o;
    o.x = pack2(a0, a1);
    o.y = pack2(a2, a3);
    aggh2[(size_t)row * 32 + sl] = o;
  }
}

// ---------------- GEMM1 MFMA ----------------
__global__ __launch_bounds__(256) void k_gemm1(const short* __restrict__ aggh,
                                               const short* __restrict__ w1t,
                                               const float* __restrict__ b1,
                                               short* __restrict__ h1, int M) {
  int wid = threadIdx.x >> 6;
  int lane = threadIdx.x & 63;
  int row0 = blockIdx.x * 32;
  int col0 = wid * 64;
  int r = lane & 15, g = lane >> 4;

  s16x8 bfrag[4][4];
  const short* wp = w1t + (size_t)(col0 + r) * F_IN + g * 8;
#pragma unroll
  for (int cf = 0; cf < 4; ++cf)
#pragma unroll
    for (int ks = 0; ks < 4; ++ks)
      bfrag[cf][ks] = *(const s16x8*)(wp + cf * 16 * F_IN + ks * 32);

  f32x4 acc[2][4] = {};
  const short* ap = aggh + (size_t)(row0 + r) * F_IN + g * 8;
#pragma unroll
  for (int ks = 0; ks < 4; ++ks) {
    s16x8 a0 = *(const s16x8*)(ap + ks * 32);
    s16x8 a1 = *(const s16x8*)(ap + 16 * F_IN + ks * 32);
#pragma unroll
    for (int cf = 0; cf < 4; ++cf) {
      acc[0][cf] = __builtin_amdgcn_mfma_f32_16x16x32_bf16(a0, bfrag[cf][ks], acc[0][cf], 0, 0, 0);
      acc[1][cf] = __builtin_amdgcn_mfma_f32_16x16x32_bf16(a1, bfrag[cf][ks], acc[1][cf], 0, 0, 0);
    }
  }

  float bb[4];
#pragma unroll
  for (int cf = 0; cf < 4; ++cf) bb[cf] = b1[col0 + cf * 16 + r];
#pragma unroll
  for (int rf = 0; rf < 2; ++rf)
#pragma unroll
    for (int cf = 0; cf < 4; ++cf)
#pragma unroll
      for (int j = 0; j < 4; ++j) {
        int orow = row0 + rf * 16 + g * 4 + j;
        if (orow < M) {
          float v = fmaxf(acc[rf][cf][j] + bb[cf], 0.f);
          h1[(size_t)orow * HDIM + col0 + cf * 16 + r] = (short)bf16_rne(v);
        }
      }
}

// ---------------- GEMM2 MFMA ----------------
__global__ __launch_bounds__(256) void k_gemm2(const short* __restrict__ h1,
                                               const short* __restrict__ w2t,
                                               float* __restrict__ T, int M) {
  int wid = threadIdx.x >> 6;
  int lane = threadIdx.x & 63;
  int row0 = blockIdx.x * 128 + wid * 32;
  int r = lane & 15, g = lane >> 4;

  s16x8 bfrag[2][8];
  const short* wp = w2t + (size_t)r * HDIM + g * 8;
#pragma unroll
  for (int cf = 0; cf < 2; ++cf)
#pragma unroll
    for (int ks = 0; ks < 8; ++ks)
      bfrag[cf][ks] = *(const s16x8*)(wp + cf * 16 * HDIM + ks * 32);

  f32x4 acc[2][2] = {};
  const short* ap = h1 + (size_t)(row0 + r) * HDIM + g * 8;
#pragma unroll
  for (int ks = 0; ks < 8; ++ks) {
    s16x8 a0 = *(const s16x8*)(ap + ks * 32);
    s16x8 a1 = *(const s16x8*)(ap + 16 * HDIM + ks * 32);
#pragma unroll
    for (int cf = 0; cf < 2; ++cf) {
      acc[0][cf] = __builtin_amdgcn_mfma_f32_16x16x32_bf16(a0, bfrag[cf][ks], acc[0][cf], 0, 0, 0);
      acc[1][cf] = __builtin_amdgcn_mfma_f32_16x16x32_bf16(a1, bfrag[cf][ks], acc[1][cf], 0, 0, 0);
    }
  }
#pragma unroll
  for (int rf = 0; rf < 2; ++rf)
#pragma unroll
    for (int cf = 0; cf < 2; ++cf)
#pragma unroll
      for (int j = 0; j < 4; ++j) {
        int orow = row0 + rf * 16 + g * 4 + j;
        if (orow < M) T[(size_t)orow * CDIM + cf * 16 + r] = acc[rf][cf][j];
      }
}

// ---------------- layer-2 aggregation + bias + log_softmax: full wave/row ----------------
__global__ __launch_bounds__(256) void k_agg2(const float* __restrict__ T,
                                              const int2* __restrict__ srcs2,
                                              const int* __restrict__ offs,
                                              const float* __restrict__ dinv,
                                              const float* __restrict__ b2,
                                              float* __restrict__ out, int N) {
  int row = (blockIdx.x * 256 + threadIdx.x) >> 6;
  int lane = threadIdx.x & 63;
  if (row >= N) return;
  int half = lane >> 5;
  int sl = lane & 31;
  float dd = dinv[row];
  float acc = 0.f;
  if (half == 0) acc = T[(size_t)row * CDIM + sl] * dd * dd + b2[sl];
  int beg = offs[row], end = offs[row + 1];
  int k = beg + half;
  for (; k + 2 < end; k += 4) {
    int2 s0 = srcs2[k];
    int2 s1 = srcs2[k + 2];
    float t0 = T[(size_t)s0.x * CDIM + sl];
    float t1 = T[(size_t)s1.x * CDIM + sl];
    acc = fmaf(t0, __int_as_float(s0.y) * dd, acc);
    acc = fmaf(t1, __int_as_float(s1.y) * dd, acc);
  }
  if (k < end) {
    int2 s0 = srcs2[k];
    acc = fmaf(T[(size_t)s0.x * CDIM + sl], __int_as_float(s0.y) * dd, acc);
  }
  acc += __shfl_xor(acc, 32, 64);
  float m = acc;
#pragma unroll
  for (int w = 16; w >= 1; w >>= 1) m = fmaxf(m, __shfl_xor(m, w, 32));
  float e = __expf(acc - m);
  float ssum = e;
#pragma unroll
  for (int w = 16; w >= 1; w >>= 1) ssum += __shfl_xor(ssum, w, 32);
  if (half == 0) out[(size_t)row * CDIM + sl] = acc - m - __logf(ssum);
}

extern "C" void kernel_launch(void* const* d_in, const int* in_sizes, int n_in,
                              void* d_out, int out_size, void* d_ws, size_t ws_size,
                              hipStream_t stream) {
  const float* x  = (const float*)d_in[0];
  const int*   ei = (const int*)d_in[1];
  const float* W1 = (const float*)d_in[2];
  const float* b1 = (const float*)d_in[3];
  const float* W2 = (const float*)d_in[4];
  const float* b2 = (const float*)d_in[5];
  float* out = (float*)d_out;
  int N = in_sizes[0] / F_IN;
  int E = in_sizes[1] / 2;

  char* base = (char*)d_ws;
  size_t o = 0;
  auto carve = [&](size_t bytes) { char* p = base + o; o += (bytes + 255) & ~(size_t)255; return p; };
  float*    dinv  = (float*)carve((size_t)N * 4);
  int*      offs  = (int*)carve((size_t)(N + 1) * 4);
  int2*     srcs2 = (int2*)carve((size_t)E * 8);
  unsigned* xh    = (unsigned*)carve((size_t)N * 64 * 4);
  unsigned* aggh  = (unsigned*)carve((size_t)N * 64 * 4);
  short*    h1    = (short*)carve((size_t)N * HDIM * 2);
  float*    T     = (float*)carve((size_t)N * CDIM * 4);
  short*    W1t   = (short*)carve((size_t)HDIM * F_IN * 2);
  short*    W2t   = (short*)carve((size_t)CDIM * HDIM * 2);

  // bucket/CSR scratch lives in h1 (dead until GEMM1 writes h1)
  int nbuc = (N + (1 << RSH) - 1) >> RSH;
  int n4 = (nbuc + 3) / 4;
  int* cnt   = (int*)h1;            // N
  int* part  = cnt + N;             // ~N/1024
  int* bcnt  = part + 256;          // n4*4 (padded)
  int* boffs = bcnt + n4 * 4;       // nbuc+1 (+pad)
  int* bcur  = boffs + n4 * 4 + 8;  // n4*4
  unsigned* barray = (unsigned*)(bcur + n4 * 4);  // E

  int nb = (N + SCHUNK - 1) / SCHUNK;
  int ng = (N + GRP - 1) / GRP;

  long long n2 = (long long)N * 64;
  k_cvt_x<<<(int)((n2 + 255) / 256), 256, 0, stream>>>((const float2*)x, xh, n2);
  k_cvt_w<<<(F_IN * HDIM + HDIM * CDIM + 255) / 256, 256, 0, stream>>>(W1, W2, W1t, W2t);

  // bucket build
  hipMemsetAsync(bcnt, 0, (size_t)n4 * 16, stream);
  k_bcount<<<(E + 255) / 256, 256, 0, stream>>>(ei, bcnt, E);
  k_bscan<<<1, 1024, 0, stream>>>((const int4*)bcnt, boffs, bcur, n4, nbuc, E);
  k_bscatter<<<(E + 255) / 256, 256, 0, stream>>>(ei, bcur, barray, E);
  k_cntfine<<<ng, 256, 0, stream>>>(barray, boffs, cnt, dinv, N, nbuc);

  // offs scan
  k_part<<<nb, 256, 0, stream>>>(cnt, part, N);
  k_scanpart<<<1, 1024, 0, stream>>>(part, offs, nb, N, E);
  k_offs<<<nb, 256, 0, stream>>>(cnt, part, offs, N);

  // fine CSR fill
  k_fillfine<<<ng, 256, 0, stream>>>(barray, boffs, offs, dinv, srcs2, N, nbuc);

  // layer 1
  k_agg1<<<(N + 3) / 4, 256, 0, stream>>>((const uint2*)xh, srcs2, offs, dinv, (uint2*)aggh, N);
  k_gemm1<<<(N + 31) / 32, 256, 0, stream>>>((const short*)aggh, W1t, b1, h1, N);

  // layer 2
  k_gemm2<<<(N + 127) / 128, 256, 0, stream>>>(h1, W2t, T, N);
  k_agg2<<<(N + 3) / 4, 256, 0, stream>>>(T, srcs2, offs, dinv, b2, out, N);
}

// Round 7
// 286.510 us; speedup vs baseline: 1.5117x; 1.5117x over previous
//
#include <hip/hip_runtime.h>
#include <math.h>

#define F_IN 128
#define HDIM 256
#define CDIM 32
#define SCHUNK 1024
#define PSH 9
#define PSZ 512        // dsts per partition
#define CHUNK 8192     // edges per partition-pass block

typedef __attribute__((ext_vector_type(8))) short s16x8;
typedef __attribute__((ext_vector_type(4))) float f32x4;

__device__ __forceinline__ unsigned bf16_rne(float f) {
  unsigned u = __float_as_uint(f);
  u += 0x7fffu + ((u >> 16) & 1u);
  return u >> 16;
}
__device__ __forceinline__ unsigned pack2(float lo, float hi) {
  return (bf16_rne(hi) << 16) | bf16_rne(lo);
}
__device__ __forceinline__ float bflo(unsigned u) { return __uint_as_float(u << 16); }
__device__ __forceinline__ float bfhi(unsigned u) { return __uint_as_float(u & 0xffff0000u); }

// ---------------- pass 1: partition counts ----------------
__global__ __launch_bounds__(256) void k_pcount(const int* __restrict__ ei,
                                                int* __restrict__ pcnt, int E) {
  __shared__ int hist[256];
  int tid = threadIdx.x;
  hist[tid] = 0;
  __syncthreads();
  int base = blockIdx.x * CHUNK;
  int n = E - base; if (n > CHUNK) n = CHUNK;
  for (int i = tid; i < n; i += 256)
    atomicAdd(&hist[ei[(size_t)E + base + i] >> PSH], 1);
  __syncthreads();
  if (hist[tid] > 0) atomicAdd(&pcnt[tid], hist[tid]);
}

__global__ __launch_bounds__(256) void k_pscan(const int* __restrict__ pcnt,
                                               int* __restrict__ pbase,
                                               int* __restrict__ pcur, int NP, int E) {
  __shared__ int sh[256];
  int tid = threadIdx.x;
  int v = (tid < NP) ? pcnt[tid] : 0;
  sh[tid] = v;
  __syncthreads();
  for (int off = 1; off < 256; off <<= 1) {
    int t = (tid >= off) ? sh[tid - off] : 0;
    __syncthreads();
    sh[tid] += t;
    __syncthreads();
  }
  if (tid < NP) { pbase[tid] = sh[tid] - v; pcur[tid] = sh[tid] - v; }
  if (tid == 0) pbase[NP] = E;
}

// pass 2: LDS-staged partition scatter — per-block contiguous runs per partition
__global__ __launch_bounds__(256) void k_pscatter(const int* __restrict__ ei,
                                                  int* __restrict__ pcur,
                                                  unsigned* __restrict__ pbuf, int E) {
  __shared__ int hist[256];
  __shared__ int cur[256];
  int tid = threadIdx.x;
  hist[tid] = 0;
  __syncthreads();
  int base = blockIdx.x * CHUNK;
  int n = E - base; if (n > CHUNK) n = CHUNK;
  for (int i = tid; i < n; i += 256)
    atomicAdd(&hist[ei[(size_t)E + base + i] >> PSH], 1);
  __syncthreads();
  if (hist[tid] > 0) cur[tid] = atomicAdd(&pcur[tid], hist[tid]);
  __syncthreads();
  for (int i = tid; i < n; i += 256) {
    int s = ei[base + i];
    int d = ei[(size_t)E + base + i];
    int p = d >> PSH;
    int pos = atomicAdd(&cur[p], 1);
    pbuf[pos] = ((unsigned)s << PSH) | (unsigned)(d & (PSZ - 1));
  }
}

// per-partition histogram -> cnt + dinv (coalesced, no global atomics)
__global__ __launch_bounds__(256) void k_cntfine2(const unsigned* __restrict__ pbuf,
                                                  const int* __restrict__ pbase,
                                                  int* __restrict__ cnt,
                                                  float* __restrict__ dinv, int N) {
  __shared__ int hist[PSZ];
  int g = blockIdx.x, tid = threadIdx.x;
  for (int i = tid; i < PSZ; i += 256) hist[i] = 0;
  __syncthreads();
  int e0 = pbase[g], e1 = pbase[g + 1];
  for (int i = e0 + tid; i < e1; i += 256)
    atomicAdd(&hist[pbuf[i] & (PSZ - 1)], 1);
  __syncthreads();
  int d0 = g << PSH;
  for (int i = tid; i < PSZ; i += 256) {
    int d = d0 + i;
    if (d < N) {
      int c = hist[i];
      cnt[d] = c;
      dinv[d] = rsqrtf((float)c + 1.0f);
    }
  }
}

// ---------------- offs scan over per-dst counts ----------------
__global__ __launch_bounds__(256) void k_part(const int* __restrict__ cnt,
                                              int* __restrict__ part, int N) {
  __shared__ int red[256];
  int tid = threadIdx.x;
  int base = blockIdx.x * SCHUNK + tid * 4;
  int s = 0;
#pragma unroll
  for (int i = 0; i < 4; ++i) {
    int idx = base + i;
    if (idx < N) s += cnt[idx];
  }
  red[tid] = s;
  __syncthreads();
  for (int off = 128; off >= 1; off >>= 1) {
    if (tid < off) red[tid] += red[tid + off];
    __syncthreads();
  }
  if (tid == 0) part[blockIdx.x] = red[0];
}

__global__ __launch_bounds__(1024) void k_scanpart(int* __restrict__ part,
                                                   int* __restrict__ offs,
                                                   int nb, int N, int Etot) {
  __shared__ int sh[1024];
  int tid = threadIdx.x;
  int v = (tid < nb) ? part[tid] : 0;
  sh[tid] = v;
  __syncthreads();
  for (int off = 1; off < 1024; off <<= 1) {
    int t = (tid >= off) ? sh[tid - off] : 0;
    __syncthreads();
    sh[tid] += t;
    __syncthreads();
  }
  if (tid < nb) part[tid] = sh[tid] - v;
  if (tid == 0) offs[N] = Etot;
}

__global__ __launch_bounds__(256) void k_offs(const int* __restrict__ cnt,
                                              const int* __restrict__ part,
                                              int* __restrict__ offs, int N) {
  __shared__ int sh[256];
  int tid = threadIdx.x;
  int base = blockIdx.x * SCHUNK + tid * 4;
  int v[4];
  int s = 0;
#pragma unroll
  for (int i = 0; i < 4; ++i) {
    int idx = base + i;
    v[i] = (idx < N) ? cnt[idx] : 0;
    s += v[i];
  }
  sh[tid] = s;
  __syncthreads();
  for (int off = 1; off < 256; off <<= 1) {
    int t = (tid >= off) ? sh[tid - off] : 0;
    __syncthreads();
    sh[tid] += t;
    __syncthreads();
  }
  int run = part[blockIdx.x] + sh[tid] - s;
#pragma unroll
  for (int i = 0; i < 4; ++i) {
    int idx = base + i;
    if (idx < N) {
      offs[idx] = run;
      run += v[i];
    }
  }
}

// per-partition fine fill: writes confined to ~65KB contiguous region per CU
__global__ __launch_bounds__(256) void k_fillpart(const unsigned* __restrict__ pbuf,
                                                  const int* __restrict__ pbase,
                                                  const int* __restrict__ offs,
                                                  const float* __restrict__ dinv,
                                                  int2* __restrict__ srcs2, int N) {
  __shared__ int cur[PSZ];
  int g = blockIdx.x, tid = threadIdx.x;
  int d0 = g << PSH;
  for (int i = tid; i < PSZ; i += 256) {
    int d = d0 + i;
    cur[i] = (d < N) ? offs[d] : 0;
  }
  __syncthreads();
  int e0 = pbase[g], e1 = pbase[g + 1];
  for (int i = e0 + tid; i < e1; i += 256) {
    unsigned v = pbuf[i];
    int dl = v & (PSZ - 1);
    int src = v >> PSH;
    int pos = atomicAdd(&cur[dl], 1);
    int2 w;
    w.x = src;
    w.y = __float_as_int(dinv[src]);
    srcs2[pos] = w;
  }
}

// ---------------- conversions ----------------
__global__ void k_cvt_x(const float2* __restrict__ x, unsigned* __restrict__ xh, long long n2) {
  long long i = (long long)blockIdx.x * blockDim.x + threadIdx.x;
  if (i >= n2) return;
  float2 v = x[i];
  xh[i] = pack2(v.x, v.y);
}

__global__ void k_cvt_w(const float* __restrict__ W1, const float* __restrict__ W2,
                        short* __restrict__ W1t, short* __restrict__ W2t) {
  int t = blockIdx.x * blockDim.x + threadIdx.x;
  if (t < F_IN * HDIM) {
    int c = t >> 7, k = t & 127;
    W1t[t] = (short)bf16_rne(W1[k * HDIM + c]);
  } else {
    int t2 = t - F_IN * HDIM;
    if (t2 < HDIM * CDIM) {
      int n = t2 >> 8, k = t2 & 255;
      W2t[t2] = (short)bf16_rne(W2[k * CDIM + n]);
    }
  }
}

// ---------------- layer-1 aggregation: full wave/row, even/odd halves, 4 deep ----------------
__global__ __launch_bounds__(256) void k_agg1(const uint2* __restrict__ xh2,
                                              const int2* __restrict__ srcs2,
                                              const int* __restrict__ offs,
                                              const float* __restrict__ dinv,
                                              uint2* __restrict__ aggh2, int N) {
  int row = (blockIdx.x * 256 + threadIdx.x) >> 6;
  int lane = threadIdx.x & 63;
  if (row >= N) return;
  int half = lane >> 5;
  int sl = lane & 31;
  float dd = dinv[row];
  float a0 = 0.f, a1 = 0.f, a2 = 0.f, a3 = 0.f;
  if (half == 0) {
    uint2 u = xh2[(size_t)row * 32 + sl];
    float sc = dd * dd;
    a0 = bflo(u.x) * sc; a1 = bfhi(u.x) * sc;
    a2 = bflo(u.y) * sc; a3 = bfhi(u.y) * sc;
  }
  int beg = offs[row], end = offs[row + 1];
  int k = beg + half;
  while (k + 6 < end) {
    int2 s0 = srcs2[k];
    int2 s1 = srcs2[k + 2];
    int2 s2 = srcs2[k + 4];
    int2 s3 = srcs2[k + 6];
    uint2 v0 = xh2[(size_t)s0.x * 32 + sl];
    uint2 v1 = xh2[(size_t)s1.x * 32 + sl];
    uint2 v2 = xh2[(size_t)s2.x * 32 + sl];
    uint2 v3 = xh2[(size_t)s3.x * 32 + sl];
    float n0 = __int_as_float(s0.y) * dd;
    float n1 = __int_as_float(s1.y) * dd;
    float n2 = __int_as_float(s2.y) * dd;
    float n3 = __int_as_float(s3.y) * dd;
    a0 = fmaf(bflo(v0.x), n0, a0); a1 = fmaf(bfhi(v0.x), n0, a1);
    a2 = fmaf(bflo(v0.y), n0, a2); a3 = fmaf(bfhi(v0.y), n0, a3);
    a0 = fmaf(bflo(v1.x), n1, a0); a1 = fmaf(bfhi(v1.x), n1, a1);
    a2 = fmaf(bflo(v1.y), n1, a2); a3 = fmaf(bfhi(v1.y), n1, a3);
    a0 = fmaf(bflo(v2.x), n2, a0); a1 = fmaf(bfhi(v2.x), n2, a1);
    a2 = fmaf(bflo(v2.y), n2, a2); a3 = fmaf(bfhi(v2.y), n2, a3);
    a0 = fmaf(bflo(v3.x), n3, a0); a1 = fmaf(bfhi(v3.x), n3, a1);
    a2 = fmaf(bflo(v3.y), n3, a2); a3 = fmaf(bfhi(v3.y), n3, a3);
    k += 8;
  }
  while (k < end) {
    int2 s0 = srcs2[k];
    uint2 v0 = xh2[(size_t)s0.x * 32 + sl];
    float n0 = __int_as_float(s0.y) * dd;
    a0 = fmaf(bflo(v0.x), n0, a0); a1 = fmaf(bfhi(v0.x), n0, a1);
    a2 = fmaf(bflo(v0.y), n0, a2); a3 = fmaf(bfhi(v0.y), n0, a3);
    k += 2;
  }
  a0 += __shfl_xor(a0, 32, 64);
  a1 += __shfl_xor(a1, 32, 64);
  a2 += __shfl_xor(a2, 32, 64);
  a3 += __shfl_xor(a3, 32, 64);
  if (half == 0) {
    uint2 o;
    o.x = pack2(a0, a1);
    o.y = pack2(a2, a3);
    aggh2[(size_t)row * 32 + sl] = o;
  }
}

// ---------------- GEMM1 MFMA ----------------
__global__ __launch_bounds__(256) void k_gemm1(const short* __restrict__ aggh,
                                               const short* __restrict__ w1t,
                                               const float* __restrict__ b1,
                                               short* __restrict__ h1, int M) {
  int wid = threadIdx.x >> 6;
  int lane = threadIdx.x & 63;
  int row0 = blockIdx.x * 32;
  int col0 = wid * 64;
  int r = lane & 15, g = lane >> 4;

  s16x8 bfrag[4][4];
  const short* wp = w1t + (size_t)(col0 + r) * F_IN + g * 8;
#pragma unroll
  for (int cf = 0; cf < 4; ++cf)
#pragma unroll
    for (int ks = 0; ks < 4; ++ks)
      bfrag[cf][ks] = *(const s16x8*)(wp + cf * 16 * F_IN + ks * 32);

  f32x4 acc[2][4] = {};
  const short* ap = aggh + (size_t)(row0 + r) * F_IN + g * 8;
#pragma unroll
  for (int ks = 0; ks < 4; ++ks) {
    s16x8 a0 = *(const s16x8*)(ap + ks * 32);
    s16x8 a1 = *(const s16x8*)(ap + 16 * F_IN + ks * 32);
#pragma unroll
    for (int cf = 0; cf < 4; ++cf) {
      acc[0][cf] = __builtin_amdgcn_mfma_f32_16x16x32_bf16(a0, bfrag[cf][ks], acc[0][cf], 0, 0, 0);
      acc[1][cf] = __builtin_amdgcn_mfma_f32_16x16x32_bf16(a1, bfrag[cf][ks], acc[1][cf], 0, 0, 0);
    }
  }

  float bb[4];
#pragma unroll
  for (int cf = 0; cf < 4; ++cf) bb[cf] = b1[col0 + cf * 16 + r];
#pragma unroll
  for (int rf = 0; rf < 2; ++rf)
#pragma unroll
    for (int cf = 0; cf < 4; ++cf)
#pragma unroll
      for (int j = 0; j < 4; ++j) {
        int orow = row0 + rf * 16 + g * 4 + j;
        if (orow < M) {
          float v = fmaxf(acc[rf][cf][j] + bb[cf], 0.f);
          h1[(size_t)orow * HDIM + col0 + cf * 16 + r] = (short)bf16_rne(v);
        }
      }
}

// ---------------- GEMM2 MFMA ----------------
__global__ __launch_bounds__(256) void k_gemm2(const short* __restrict__ h1,
                                               const short* __restrict__ w2t,
                                               float* __restrict__ T, int M) {
  int wid = threadIdx.x >> 6;
  int lane = threadIdx.x & 63;
  int row0 = blockIdx.x * 128 + wid * 32;
  int r = lane & 15, g = lane >> 4;

  s16x8 bfrag[2][8];
  const short* wp = w2t + (size_t)r * HDIM + g * 8;
#pragma unroll
  for (int cf = 0; cf < 2; ++cf)
#pragma unroll
    for (int ks = 0; ks < 8; ++ks)
      bfrag[cf][ks] = *(const s16x8*)(wp + cf * 16 * HDIM + ks * 32);

  f32x4 acc[2][2] = {};
  const short* ap = h1 + (size_t)(row0 + r) * HDIM + g * 8;
#pragma unroll
  for (int ks = 0; ks < 8; ++ks) {
    s16x8 a0 = *(const s16x8*)(ap + ks * 32);
    s16x8 a1 = *(const s16x8*)(ap + 16 * HDIM + ks * 32);
#pragma unroll
    for (int cf = 0; cf < 2; ++cf) {
      acc[0][cf] = __builtin_amdgcn_mfma_f32_16x16x32_bf16(a0, bfrag[cf][ks], acc[0][cf], 0, 0, 0);
      acc[1][cf] = __builtin_amdgcn_mfma_f32_16x16x32_bf16(a1, bfrag[cf][ks], acc[1][cf], 0, 0, 0);
    }
  }
#pragma unroll
  for (int rf = 0; rf < 2; ++rf)
#pragma unroll
    for (int cf = 0; cf < 2; ++cf)
#pragma unroll
      for (int j = 0; j < 4; ++j) {
        int orow = row0 + rf * 16 + g * 4 + j;
        if (orow < M) T[(size_t)orow * CDIM + cf * 16 + r] = acc[rf][cf][j];
      }
}

// ---------------- layer-2 aggregation + bias + log_softmax: full wave/row, 4 deep ----------------
__global__ __launch_bounds__(256) void k_agg2(const float* __restrict__ T,
                                              const int2* __restrict__ srcs2,
                                              const int* __restrict__ offs,
                                              const float* __restrict__ dinv,
                                              const float* __restrict__ b2,
                                              float* __restrict__ out, int N) {
  int row = (blockIdx.x * 256 + threadIdx.x) >> 6;
  int lane = threadIdx.x & 63;
  if (row >= N) return;
  int half = lane >> 5;
  int sl = lane & 31;
  float dd = dinv[row];
  float acc = 0.f;
  if (half == 0) acc = T[(size_t)row * CDIM + sl] * dd * dd + b2[sl];
  int beg = offs[row], end = offs[row + 1];
  int k = beg + half;
  while (k + 6 < end) {
    int2 s0 = srcs2[k];
    int2 s1 = srcs2[k + 2];
    int2 s2 = srcs2[k + 4];
    int2 s3 = srcs2[k + 6];
    float t0 = T[(size_t)s0.x * CDIM + sl];
    float t1 = T[(size_t)s1.x * CDIM + sl];
    float t2 = T[(size_t)s2.x * CDIM + sl];
    float t3 = T[(size_t)s3.x * CDIM + sl];
    acc = fmaf(t0, __int_as_float(s0.y) * dd, acc);
    acc = fmaf(t1, __int_as_float(s1.y) * dd, acc);
    acc = fmaf(t2, __int_as_float(s2.y) * dd, acc);
    acc = fmaf(t3, __int_as_float(s3.y) * dd, acc);
    k += 8;
  }
  while (k < end) {
    int2 s0 = srcs2[k];
    acc = fmaf(T[(size_t)s0.x * CDIM + sl], __int_as_float(s0.y) * dd, acc);
    k += 2;
  }
  acc += __shfl_xor(acc, 32, 64);
  float m = acc;
#pragma unroll
  for (int w = 16; w >= 1; w >>= 1) m = fmaxf(m, __shfl_xor(m, w, 32));
  float e = __expf(acc - m);
  float ssum = e;
#pragma unroll
  for (int w = 16; w >= 1; w >>= 1) ssum += __shfl_xor(ssum, w, 32);
  if (half == 0) out[(size_t)row * CDIM + sl] = acc - m - __logf(ssum);
}

extern "C" void kernel_launch(void* const* d_in, const int* in_sizes, int n_in,
                              void* d_out, int out_size, void* d_ws, size_t ws_size,
                              hipStream_t stream) {
  const float* x  = (const float*)d_in[0];
  const int*   ei = (const int*)d_in[1];
  const float* W1 = (const float*)d_in[2];
  const float* b1 = (const float*)d_in[3];
  const float* W2 = (const float*)d_in[4];
  const float* b2 = (const float*)d_in[5];
  float* out = (float*)d_out;
  int N = in_sizes[0] / F_IN;
  int E = in_sizes[1] / 2;

  char* base = (char*)d_ws;
  size_t o = 0;
  auto carve = [&](size_t bytes) { char* p = base + o; o += (bytes + 255) & ~(size_t)255; return p; };
  float*    dinv  = (float*)carve((size_t)N * 4);
  int*      offs  = (int*)carve((size_t)(N + 1) * 4);
  int2*     srcs2 = (int2*)carve((size_t)E * 8);
  unsigned* xh    = (unsigned*)carve((size_t)N * 64 * 4);
  unsigned* aggh  = (unsigned*)carve((size_t)N * 64 * 4);
  short*    h1    = (short*)carve((size_t)N * HDIM * 2);
  float*    T     = (float*)carve((size_t)N * CDIM * 4);
  short*    W1t   = (short*)carve((size_t)HDIM * F_IN * 2);
  short*    W2t   = (short*)carve((size_t)CDIM * HDIM * 2);

  // CSR scratch lives in h1 (dead until GEMM1 writes h1)
  int NP = (N + PSZ - 1) >> PSH;   // partitions (<=256 for N<=131072)
  int* cnt   = (int*)h1;           // N
  int* part  = cnt + N;            // 256
  int* pcnt  = part + 256;         // 256
  int* pbase = pcnt + 256;         // NP+1 (+pad)
  int* pcur  = pbase + 512;        // 256
  unsigned* pbuf = (unsigned*)(pcur + 256);  // E

  int nb = (N + SCHUNK - 1) / SCHUNK;
  int nc = (E + CHUNK - 1) / CHUNK;

  long long n2 = (long long)N * 64;
  k_cvt_x<<<(int)((n2 + 255) / 256), 256, 0, stream>>>((const float2*)x, xh, n2);
  k_cvt_w<<<(F_IN * HDIM + HDIM * CDIM + 255) / 256, 256, 0, stream>>>(W1, W2, W1t, W2t);

  // partition build (LDS-staged two-pass)
  hipMemsetAsync(pcnt, 0, 256 * 4, stream);
  k_pcount<<<nc, 256, 0, stream>>>(ei, pcnt, E);
  k_pscan<<<1, 256, 0, stream>>>(pcnt, pbase, pcur, NP, E);
  k_pscatter<<<nc, 256, 0, stream>>>(ei, pcur, pbuf, E);
  k_cntfine2<<<NP, 256, 0, stream>>>(pbuf, pbase, cnt, dinv, N);

  // offs scan
  k_part<<<nb, 256, 0, stream>>>(cnt, part, N);
  k_scanpart<<<1, 1024, 0, stream>>>(part, offs, nb, N, E);
  k_offs<<<nb, 256, 0, stream>>>(cnt, part, offs, N);

  // fine CSR fill
  k_fillpart<<<NP, 256, 0, stream>>>(pbuf, pbase, offs, dinv, srcs2, N);

  // layer 1
  k_agg1<<<(N + 3) / 4, 256, 0, stream>>>((const uint2*)xh, srcs2, offs, dinv, (uint2*)aggh, N);
  k_gemm1<<<(N + 31) / 32, 256, 0, stream>>>((const short*)aggh, W1t, b1, h1, N);

  // layer 2
  k_gemm2<<<(N + 127) / 128, 256, 0, stream>>>(h1, W2t, T, N);
  k_agg2<<<(N + 3) / 4, 256, 0, stream>>>(T, srcs2, offs, dinv, b2, out, N);
}

// Round 8
// 264.247 us; speedup vs baseline: 1.6391x; 1.0842x over previous
//
#include <hip/hip_runtime.h>
#include <math.h>

#define F_IN 128
#define HDIM 256
#define CDIM 32
#define PSH 9
#define PSZ 512        // dsts per partition
#define CHUNK 8192     // edges per partition-pass block

typedef __attribute__((ext_vector_type(8))) short s16x8;
typedef __attribute__((ext_vector_type(4))) float f32x4;

__device__ __forceinline__ unsigned bf16_rne(float f) {
  unsigned u = __float_as_uint(f);
  u += 0x7fffu + ((u >> 16) & 1u);
  return u >> 16;
}
__device__ __forceinline__ unsigned pack2(float lo, float hi) {
  return (bf16_rne(hi) << 16) | bf16_rne(lo);
}
__device__ __forceinline__ float bflo(unsigned u) { return __uint_as_float(u << 16); }
__device__ __forceinline__ float bfhi(unsigned u) { return __uint_as_float(u & 0xffff0000u); }

// ---------------- pass 1: partition counts ----------------
__global__ __launch_bounds__(256) void k_pcount(const int* __restrict__ ei,
                                                int* __restrict__ pcnt, int E) {
  __shared__ int hist[256];
  int tid = threadIdx.x;
  hist[tid] = 0;
  __syncthreads();
  int base = blockIdx.x * CHUNK;
  int n = E - base; if (n > CHUNK) n = CHUNK;
  for (int i = tid; i < n; i += 256)
    atomicAdd(&hist[ei[(size_t)E + base + i] >> PSH], 1);
  __syncthreads();
  if (hist[tid] > 0) atomicAdd(&pcnt[tid], hist[tid]);
}

__global__ __launch_bounds__(256) void k_pscan(const int* __restrict__ pcnt,
                                               int* __restrict__ pbase,
                                               int* __restrict__ pcur,
                                               int* __restrict__ offs,
                                               int NP, int N, int E) {
  __shared__ int sh[256];
  int tid = threadIdx.x;
  int v = (tid < NP) ? pcnt[tid] : 0;
  sh[tid] = v;
  __syncthreads();
  for (int off = 1; off < 256; off <<= 1) {
    int t = (tid >= off) ? sh[tid - off] : 0;
    __syncthreads();
    sh[tid] += t;
    __syncthreads();
  }
  if (tid < NP) { pbase[tid] = sh[tid] - v; pcur[tid] = sh[tid] - v; }
  if (tid == 0) { pbase[NP] = E; offs[N] = E; }
}

// pass 2: LDS-staged partition scatter
__global__ __launch_bounds__(256) void k_pscatter(const int* __restrict__ ei,
                                                  int* __restrict__ pcur,
                                                  unsigned* __restrict__ pbuf, int E) {
  __shared__ int hist[256];
  __shared__ int cur[256];
  int tid = threadIdx.x;
  hist[tid] = 0;
  __syncthreads();
  int base = blockIdx.x * CHUNK;
  int n = E - base; if (n > CHUNK) n = CHUNK;
  for (int i = tid; i < n; i += 256)
    atomicAdd(&hist[ei[(size_t)E + base + i] >> PSH], 1);
  __syncthreads();
  if (hist[tid] > 0) cur[tid] = atomicAdd(&pcur[tid], hist[tid]);
  __syncthreads();
  for (int i = tid; i < n; i += 256) {
    int s = ei[base + i];
    int d = ei[(size_t)E + base + i];
    int p = d >> PSH;
    int pos = atomicAdd(&cur[p], 1);
    pbuf[pos] = ((unsigned)s << PSH) | (unsigned)(d & (PSZ - 1));
  }
}

// per-partition histogram + LDS scan -> dinv + offs directly (no global cnt/scan)
__global__ __launch_bounds__(256) void k_cnt2(const unsigned* __restrict__ pbuf,
                                              const int* __restrict__ pbase,
                                              int* __restrict__ offs,
                                              float* __restrict__ dinv, int N) {
  __shared__ int hist[PSZ];
  __shared__ int sh[256];
  int g = blockIdx.x, tid = threadIdx.x;
  hist[tid] = 0;
  hist[tid + 256] = 0;
  __syncthreads();
  int e0 = pbase[g], e1 = pbase[g + 1];
  for (int i = e0 + tid; i < e1; i += 256)
    atomicAdd(&hist[pbuf[i] & (PSZ - 1)], 1);
  __syncthreads();
  int v0 = hist[2 * tid], v1 = hist[2 * tid + 1];
  int s = v0 + v1;
  sh[tid] = s;
  __syncthreads();
  for (int off = 1; off < 256; off <<= 1) {
    int t = (tid >= off) ? sh[tid - off] : 0;
    __syncthreads();
    sh[tid] += t;
    __syncthreads();
  }
  int run = pbase[g] + sh[tid] - s;
  int d = (g << PSH) + 2 * tid;
  if (d < N) { offs[d] = run; dinv[d] = rsqrtf((float)v0 + 1.0f); }
  if (d + 1 < N) { offs[d + 1] = run + v0; dinv[d + 1] = rsqrtf((float)v1 + 1.0f); }
}

// per-partition fine fill
__global__ __launch_bounds__(256) void k_fillpart(const unsigned* __restrict__ pbuf,
                                                  const int* __restrict__ pbase,
                                                  const int* __restrict__ offs,
                                                  const float* __restrict__ dinv,
                                                  int2* __restrict__ srcs2, int N) {
  __shared__ int cur[PSZ];
  int g = blockIdx.x, tid = threadIdx.x;
  int d0 = g << PSH;
  for (int i = tid; i < PSZ; i += 256) {
    int d = d0 + i;
    cur[i] = (d < N) ? offs[d] : 0;
  }
  __syncthreads();
  int e0 = pbase[g], e1 = pbase[g + 1];
  for (int i = e0 + tid; i < e1; i += 256) {
    unsigned v = pbuf[i];
    int dl = v & (PSZ - 1);
    int src = v >> PSH;
    int pos = atomicAdd(&cur[dl], 1);
    int2 w;
    w.x = src;
    w.y = __float_as_int(dinv[src]);
    srcs2[pos] = w;
  }
}

// ---------------- conversions ----------------
__global__ void k_cvt_x(const float2* __restrict__ x, unsigned* __restrict__ xh, long long n2) {
  long long i = (long long)blockIdx.x * blockDim.x + threadIdx.x;
  if (i >= n2) return;
  float2 v = x[i];
  xh[i] = pack2(v.x, v.y);
}

__global__ void k_cvt_w(const float* __restrict__ W1, const float* __restrict__ W2,
                        short* __restrict__ W1t, short* __restrict__ W2t) {
  int t = blockIdx.x * blockDim.x + threadIdx.x;
  if (t < F_IN * HDIM) {
    int c = t >> 7, k = t & 127;
    W1t[t] = (short)bf16_rne(W1[k * HDIM + c]);
  } else {
    int t2 = t - F_IN * HDIM;
    if (t2 < HDIM * CDIM) {
      int n = t2 >> 8, k = t2 & 255;
      W2t[t2] = (short)bf16_rne(W2[k * CDIM + n]);
    }
  }
}

// ---------------- layer-1 aggregation: quarter-wave (16 lanes x uint4) per edge ----------------
__global__ __launch_bounds__(256) void k_agg1(const uint4* __restrict__ xh4,
                                              const int2* __restrict__ srcs2,
                                              const int* __restrict__ offs,
                                              const float* __restrict__ dinv,
                                              uint4* __restrict__ aggh4, int N) {
  int row = (blockIdx.x * 256 + threadIdx.x) >> 6;
  int lane = threadIdx.x & 63;
  if (row >= N) return;
  int grp = lane >> 4;   // 4 edge streams
  int gl = lane & 15;    // 16 lanes x 16B = 256B row
  float dd = dinv[row];
  float a0 = 0.f, a1 = 0.f, a2 = 0.f, a3 = 0.f, a4 = 0.f, a5 = 0.f, a6 = 0.f, a7 = 0.f;
  if (grp == 0) {
    uint4 u = xh4[(size_t)row * 16 + gl];
    float sc = dd * dd;
    a0 = bflo(u.x) * sc; a1 = bfhi(u.x) * sc;
    a2 = bflo(u.y) * sc; a3 = bfhi(u.y) * sc;
    a4 = bflo(u.z) * sc; a5 = bfhi(u.z) * sc;
    a6 = bflo(u.w) * sc; a7 = bfhi(u.w) * sc;
  }
  int beg = offs[row], end = offs[row + 1];
  int k = beg + grp;
#define ACC1(V, NN)                                                  \
  a0 = fmaf(bflo(V.x), NN, a0); a1 = fmaf(bfhi(V.x), NN, a1);        \
  a2 = fmaf(bflo(V.y), NN, a2); a3 = fmaf(bfhi(V.y), NN, a3);        \
  a4 = fmaf(bflo(V.z), NN, a4); a5 = fmaf(bfhi(V.z), NN, a5);        \
  a6 = fmaf(bflo(V.w), NN, a6); a7 = fmaf(bfhi(V.w), NN, a7);
  while (k + 12 < end) {
    int2 s0 = srcs2[k];
    int2 s1 = srcs2[k + 4];
    int2 s2 = srcs2[k + 8];
    int2 s3 = srcs2[k + 12];
    uint4 v0 = xh4[(size_t)s0.x * 16 + gl];
    uint4 v1 = xh4[(size_t)s1.x * 16 + gl];
    uint4 v2 = xh4[(size_t)s2.x * 16 + gl];
    uint4 v3 = xh4[(size_t)s3.x * 16 + gl];
    float n0 = __int_as_float(s0.y) * dd;
    float n1 = __int_as_float(s1.y) * dd;
    float n2 = __int_as_float(s2.y) * dd;
    float n3 = __int_as_float(s3.y) * dd;
    ACC1(v0, n0) ACC1(v1, n1) ACC1(v2, n2) ACC1(v3, n3)
    k += 16;
  }
  while (k < end) {
    int2 s0 = srcs2[k];
    uint4 v0 = xh4[(size_t)s0.x * 16 + gl];
    float n0 = __int_as_float(s0.y) * dd;
    ACC1(v0, n0)
    k += 4;
  }
#undef ACC1
  a0 += __shfl_xor(a0, 16, 64); a0 += __shfl_xor(a0, 32, 64);
  a1 += __shfl_xor(a1, 16, 64); a1 += __shfl_xor(a1, 32, 64);
  a2 += __shfl_xor(a2, 16, 64); a2 += __shfl_xor(a2, 32, 64);
  a3 += __shfl_xor(a3, 16, 64); a3 += __shfl_xor(a3, 32, 64);
  a4 += __shfl_xor(a4, 16, 64); a4 += __shfl_xor(a4, 32, 64);
  a5 += __shfl_xor(a5, 16, 64); a5 += __shfl_xor(a5, 32, 64);
  a6 += __shfl_xor(a6, 16, 64); a6 += __shfl_xor(a6, 32, 64);
  a7 += __shfl_xor(a7, 16, 64); a7 += __shfl_xor(a7, 32, 64);
  if (grp == 0) {
    uint4 o;
    o.x = pack2(a0, a1);
    o.y = pack2(a2, a3);
    o.z = pack2(a4, a5);
    o.w = pack2(a6, a7);
    aggh4[(size_t)row * 16 + gl] = o;
  }
}

// ---------------- GEMM1 MFMA ----------------
__global__ __launch_bounds__(256) void k_gemm1(const short* __restrict__ aggh,
                                               const short* __restrict__ w1t,
                                               const float* __restrict__ b1,
                                               short* __restrict__ h1, int M) {
  int wid = threadIdx.x >> 6;
  int lane = threadIdx.x & 63;
  int row0 = blockIdx.x * 32;
  int col0 = wid * 64;
  int r = lane & 15, g = lane >> 4;

  s16x8 bfrag[4][4];
  const short* wp = w1t + (size_t)(col0 + r) * F_IN + g * 8;
#pragma unroll
  for (int cf = 0; cf < 4; ++cf)
#pragma unroll
    for (int ks = 0; ks < 4; ++ks)
      bfrag[cf][ks] = *(const s16x8*)(wp + cf * 16 * F_IN + ks * 32);

  f32x4 acc[2][4] = {};
  const short* ap = aggh + (size_t)(row0 + r) * F_IN + g * 8;
#pragma unroll
  for (int ks = 0; ks < 4; ++ks) {
    s16x8 a0 = *(const s16x8*)(ap + ks * 32);
    s16x8 a1 = *(const s16x8*)(ap + 16 * F_IN + ks * 32);
#pragma unroll
    for (int cf = 0; cf < 4; ++cf) {
      acc[0][cf] = __builtin_amdgcn_mfma_f32_16x16x32_bf16(a0, bfrag[cf][ks], acc[0][cf], 0, 0, 0);
      acc[1][cf] = __builtin_amdgcn_mfma_f32_16x16x32_bf16(a1, bfrag[cf][ks], acc[1][cf], 0, 0, 0);
    }
  }

  float bb[4];
#pragma unroll
  for (int cf = 0; cf < 4; ++cf) bb[cf] = b1[col0 + cf * 16 + r];
#pragma unroll
  for (int rf = 0; rf < 2; ++rf)
#pragma unroll
    for (int cf = 0; cf < 4; ++cf)
#pragma unroll
      for (int j = 0; j < 4; ++j) {
        int orow = row0 + rf * 16 + g * 4 + j;
        if (orow < M) {
          float v = fmaxf(acc[rf][cf][j] + bb[cf], 0.f);
          h1[(size_t)orow * HDIM + col0 + cf * 16 + r] = (short)bf16_rne(v);
        }
      }
}

// ---------------- GEMM2 MFMA -> bf16 T ----------------
__global__ __launch_bounds__(256) void k_gemm2(const short* __restrict__ h1,
                                               const short* __restrict__ w2t,
                                               short* __restrict__ Th, int M) {
  int wid = threadIdx.x >> 6;
  int lane = threadIdx.x & 63;
  int row0 = blockIdx.x * 128 + wid * 32;
  int r = lane & 15, g = lane >> 4;

  s16x8 bfrag[2][8];
  const short* wp = w2t + (size_t)r * HDIM + g * 8;
#pragma unroll
  for (int cf = 0; cf < 2; ++cf)
#pragma unroll
    for (int ks = 0; ks < 8; ++ks)
      bfrag[cf][ks] = *(const s16x8*)(wp + cf * 16 * HDIM + ks * 32);

  f32x4 acc[2][2] = {};
  const short* ap = h1 + (size_t)(row0 + r) * HDIM + g * 8;
#pragma unroll
  for (int ks = 0; ks < 8; ++ks) {
    s16x8 a0 = *(const s16x8*)(ap + ks * 32);
    s16x8 a1 = *(const s16x8*)(ap + 16 * HDIM + ks * 32);
#pragma unroll
    for (int cf = 0; cf < 2; ++cf) {
      acc[0][cf] = __builtin_amdgcn_mfma_f32_16x16x32_bf16(a0, bfrag[cf][ks], acc[0][cf], 0, 0, 0);
      acc[1][cf] = __builtin_amdgcn_mfma_f32_16x16x32_bf16(a1, bfrag[cf][ks], acc[1][cf], 0, 0, 0);
    }
  }
#pragma unroll
  for (int rf = 0; rf < 2; ++rf)
#pragma unroll
    for (int cf = 0; cf < 2; ++cf)
#pragma unroll
      for (int j = 0; j < 4; ++j) {
        int orow = row0 + rf * 16 + g * 4 + j;
        if (orow < M) Th[(size_t)orow * CDIM + cf * 16 + r] = (short)bf16_rne(acc[rf][cf][j]);
      }
}

// ---------------- layer-2 aggregation + bias + log_softmax: 16-lane groups on bf16 T ----------------
__global__ __launch_bounds__(256) void k_agg2(const unsigned* __restrict__ Th,
                                              const int2* __restrict__ srcs2,
                                              const int* __restrict__ offs,
                                              const float* __restrict__ dinv,
                                              const float* __restrict__ b2,
                                              float* __restrict__ out, int N) {
  int row = (blockIdx.x * 256 + threadIdx.x) >> 6;
  int lane = threadIdx.x & 63;
  if (row >= N) return;
  int grp = lane >> 4;   // 4 edge streams
  int gl = lane & 15;    // 16 lanes x 4B(2 bf16) = 64B row
  float dd = dinv[row];
  float a0 = 0.f, a1 = 0.f;
  if (grp == 0) {
    unsigned u = Th[(size_t)row * 16 + gl];
    float sc = dd * dd;
    float2 bb = ((const float2*)b2)[gl];
    a0 = bflo(u) * sc + bb.x;
    a1 = bfhi(u) * sc + bb.y;
  }
  int beg = offs[row], end = offs[row + 1];
  int k = beg + grp;
  while (k + 12 < end) {
    int2 s0 = srcs2[k];
    int2 s1 = srcs2[k + 4];
    int2 s2 = srcs2[k + 8];
    int2 s3 = srcs2[k + 12];
    unsigned u0 = Th[(size_t)s0.x * 16 + gl];
    unsigned u1 = Th[(size_t)s1.x * 16 + gl];
    unsigned u2 = Th[(size_t)s2.x * 16 + gl];
    unsigned u3 = Th[(size_t)s3.x * 16 + gl];
    float n0 = __int_as_float(s0.y) * dd;
    float n1 = __int_as_float(s1.y) * dd;
    float n2 = __int_as_float(s2.y) * dd;
    float n3 = __int_as_float(s3.y) * dd;
    a0 = fmaf(bflo(u0), n0, a0); a1 = fmaf(bfhi(u0), n0, a1);
    a0 = fmaf(bflo(u1), n1, a0); a1 = fmaf(bfhi(u1), n1, a1);
    a0 = fmaf(bflo(u2), n2, a0); a1 = fmaf(bfhi(u2), n2, a1);
    a0 = fmaf(bflo(u3), n3, a0); a1 = fmaf(bfhi(u3), n3, a1);
    k += 16;
  }
  while (k < end) {
    int2 s0 = srcs2[k];
    unsigned u0 = Th[(size_t)s0.x * 16 + gl];
    float n0 = __int_as_float(s0.y) * dd;
    a0 = fmaf(bflo(u0), n0, a0); a1 = fmaf(bfhi(u0), n0, a1);
    k += 4;
  }
  a0 += __shfl_xor(a0, 16, 64); a0 += __shfl_xor(a0, 32, 64);
  a1 += __shfl_xor(a1, 16, 64); a1 += __shfl_xor(a1, 32, 64);
  // log_softmax over 32 classes held 2-per-lane across each 16-lane group
  float m = fmaxf(a0, a1);
#pragma unroll
  for (int w = 8; w >= 1; w >>= 1) m = fmaxf(m, __shfl_xor(m, w, 64));
  float ssum = __expf(a0 - m) + __expf(a1 - m);
#pragma unroll
  for (int w = 8; w >= 1; w >>= 1) ssum += __shfl_xor(ssum, w, 64);
  float ls = m + __logf(ssum);
  if (grp == 0) {
    float2 o;
    o.x = a0 - ls;
    o.y = a1 - ls;
    ((float2*)out)[(size_t)row * 16 + gl] = o;
  }
}

extern "C" void kernel_launch(void* const* d_in, const int* in_sizes, int n_in,
                              void* d_out, int out_size, void* d_ws, size_t ws_size,
                              hipStream_t stream) {
  const float* x  = (const float*)d_in[0];
  const int*   ei = (const int*)d_in[1];
  const float* W1 = (const float*)d_in[2];
  const float* b1 = (const float*)d_in[3];
  const float* W2 = (const float*)d_in[4];
  const float* b2 = (const float*)d_in[5];
  float* out = (float*)d_out;
  int N = in_sizes[0] / F_IN;
  int E = in_sizes[1] / 2;

  char* base = (char*)d_ws;
  size_t o = 0;
  auto carve = [&](size_t bytes) { char* p = base + o; o += (bytes + 255) & ~(size_t)255; return p; };
  float*    dinv  = (float*)carve((size_t)N * 4);
  int*      offs  = (int*)carve((size_t)(N + 1) * 4);
  int2*     srcs2 = (int2*)carve((size_t)E * 8);
  unsigned* xh    = (unsigned*)carve((size_t)N * 64 * 4);
  unsigned* aggh  = (unsigned*)carve((size_t)N * 64 * 4);
  short*    h1    = (short*)carve((size_t)N * HDIM * 2);
  short*    Th    = (short*)carve((size_t)N * CDIM * 2);
  short*    W1t   = (short*)carve((size_t)HDIM * F_IN * 2);
  short*    W2t   = (short*)carve((size_t)CDIM * HDIM * 2);

  // CSR scratch lives in h1 (dead until GEMM1 writes h1)
  int NP = (N + PSZ - 1) >> PSH;
  int* pcnt  = (int*)h1;            // 256
  int* pbase = pcnt + 256;          // NP+1 (+pad)
  int* pcur  = pbase + 512;         // 256
  unsigned* pbuf = (unsigned*)(pcur + 256);  // E

  int nc = (E + CHUNK - 1) / CHUNK;

  long long n2 = (long long)N * 64;
  k_cvt_x<<<(int)((n2 + 255) / 256), 256, 0, stream>>>((const float2*)x, xh, n2);
  k_cvt_w<<<(F_IN * HDIM + HDIM * CDIM + 255) / 256, 256, 0, stream>>>(W1, W2, W1t, W2t);

  // partition build (LDS-staged two-pass)
  hipMemsetAsync(pcnt, 0, 256 * 4, stream);
  k_pcount<<<nc, 256, 0, stream>>>(ei, pcnt, E);
  k_pscan<<<1, 256, 0, stream>>>(pcnt, pbase, pcur, offs, NP, N, E);
  k_pscatter<<<nc, 256, 0, stream>>>(ei, pcur, pbuf, E);
  k_cnt2<<<NP, 256, 0, stream>>>(pbuf, pbase, offs, dinv, N);
  k_fillpart<<<NP, 256, 0, stream>>>(pbuf, pbase, offs, dinv, srcs2, N);

  // layer 1
  k_agg1<<<(N + 3) / 4, 256, 0, stream>>>((const uint4*)xh, srcs2, offs, dinv, (uint4*)aggh, N);
  k_gemm1<<<(N + 31) / 32, 256, 0, stream>>>((const short*)aggh, W1t, b1, h1, N);

  // layer 2
  k_gemm2<<<(N + 127) / 128, 256, 0, stream>>>(h1, W2t, Th, N);
  k_agg2<<<(N + 3) / 4, 256, 0, stream>>>((const unsigned*)Th, srcs2, offs, dinv, b2, out, N);
}